// Round 9
// baseline (522.072 us; speedup 1.0000x reference)
//
#include <hip/hip_runtime.h>
#include <hip/hip_bf16.h>
#include <hip/hip_fp16.h>
#include <cstdint>
#include <cstddef>
#include <cmath>

#define F_IN 256
#define HDIM 128
#define CCLS 40
#define NBMAX 1024   // max buckets (n<=65536); n=50000 -> 782

typedef short bf16x8 __attribute__((ext_vector_type(8)));
typedef float f32x4 __attribute__((ext_vector_type(4)));

__device__ inline unsigned pkbf(float a, float b) {
  __hip_bfloat162 h = __float22bfloat162_rn(make_float2(a, b));
  unsigned u;
  __builtin_memcpy(&u, &h, 4);
  return u;
}
__device__ inline unsigned short bfr(float f) {
  __hip_bfloat16 h = __float2bfloat16(f);
  unsigned short u;
  __builtin_memcpy(&u, &h, 2);
  return u;
}
__device__ inline float f16tof(unsigned short hb) {
  __half hv;
  __builtin_memcpy(&hv, &hb, 2);
  return __half2float(hv);
}
__device__ inline unsigned short ftof16(float f) {
  __half hv = __float2half(f);
  unsigned short u;
  __builtin_memcpy(&u, &hv, 2);
  return u;
}

// ---------------- prep: norm+bf16cast | W1T/W2T bf16 transpose | Wc fold | gcount zero ----------------
__global__ __launch_bounds__(256) void prep_kernel(const float* __restrict__ x,
                                                   unsigned short* __restrict__ featbf,
                                                   const float* __restrict__ W1,
                                                   const float* __restrict__ W2,
                                                   unsigned short* __restrict__ W1T,
                                                   unsigned short* __restrict__ W2T,
                                                   const float* __restrict__ We,
                                                   const float* __restrict__ be,
                                                   const float* __restrict__ Wf,
                                                   const float* __restrict__ bf,
                                                   float* __restrict__ Wc,
                                                   float* __restrict__ bc,
                                                   int* __restrict__ gcount,
                                                   int n, int nb) {
  const int b = blockIdx.x;
  const int t = threadIdx.x;
  const int nblk = (n + 3) >> 2;
  if (b < nblk) {                       // ---- row L2 norm + bf16 cast
    int wv = t >> 6, l = t & 63;
    int row = b * 4 + wv;
    if (row >= n) return;
    float4 v = *(const float4*)(x + (size_t)row * F_IN + l * 4);
    float s = v.x * v.x + v.y * v.y + v.z * v.z + v.w * v.w;
#pragma unroll
    for (int off = 32; off; off >>= 1) s += __shfl_xor(s, off, 64);
    float inv = 1.0f / fmaxf(sqrtf(s), 1e-12f);
    uint2 o = make_uint2(pkbf(v.x * inv, v.y * inv), pkbf(v.z * inv, v.w * inv));
    *(uint2*)(featbf + (size_t)row * F_IN + l * 4) = o;
  } else if (b < nblk + 192) {          // ---- W transpose + bf16
    int idx = (b - nblk) * 256 + t;
    if (idx < 128 * 256) {
      int nr = idx >> 8, k = idx & 255;
      W1T[idx] = bfr(W1[k * 128 + nr]);
    } else {
      int i2 = idx - 128 * 256;
      if (i2 < 128 * 128) {
        int nr = i2 >> 7, k = i2 & 127;
        W2T[i2] = bfr(W2[k * 128 + nr]);
      }
    }
  } else if (b == nblk + 192) {         // ---- fold Wc = We @ Wf_top, bc
    for (int i = t; i < CCLS * CCLS; i += 256) {
      int c = i / CCLS, j = i % CCLS;
      float s = 0.f;
      for (int f = 0; f < HDIM; ++f) s += We[c * HDIM + f] * Wf[f * CCLS + j];
      Wc[i] = s;
    }
    if (t < CCLS) {
      float s = bf[t];
      for (int f = 0; f < HDIM; ++f) s += be[f] * Wf[f * CCLS + t];
      bc[t] = s;
    }
  } else {                              // ---- zero gcount
    int i = (b - (nblk + 193)) * 256 + t;
    if (i < nb) gcount[i] = 0;
  }
}

// ---------------- bucket histogram (bucket = dst>>6), int4 loads ----------------
__global__ __launch_bounds__(256) void bucket_hist(const int* __restrict__ dst,
                                                   int* __restrict__ gcount, int e, int nb) {
  __shared__ int h[NBMAX];
  for (int i = threadIdx.x; i < nb; i += 256) h[i] = 0;
  __syncthreads();
  int b4 = blockIdx.x * 1024;
#pragma unroll
  for (int k = 0; k < 4; ++k) {
    int gi = b4 + k * 256 + threadIdx.x;
    int e0 = gi * 4;
    int4 d = make_int4(-1, -1, -1, -1);
    if (e0 + 3 < e) d = ((const int4*)dst)[gi];
    else if (e0 < e) {
      d.x = dst[e0];
      if (e0 + 1 < e) d.y = dst[e0 + 1];
      if (e0 + 2 < e) d.z = dst[e0 + 2];
    }
    if (d.x >= 0) atomicAdd(&h[d.x >> 6], 1);
    if (d.y >= 0) atomicAdd(&h[d.y >> 6], 1);
    if (d.z >= 0) atomicAdd(&h[d.z >> 6], 1);
    if (d.w >= 0) atomicAdd(&h[d.w >> 6], 1);
  }
  __syncthreads();
  for (int i = threadIdx.x; i < nb; i += 256)
    if (h[i]) atomicAdd(&gcount[i], h[i]);
}

// ---------------- exclusive scan of bucket counts (1 block) ----------------
__global__ __launch_bounds__(256) void bucket_scan(const int* __restrict__ gcount,
                                                   int* __restrict__ boff,
                                                   int* __restrict__ gcursor,
                                                   int* __restrict__ row_off,
                                                   int nb, int n) {
  __shared__ int part[256];
  int t = threadIdx.x;
  int v[4];
  int s = 0;
#pragma unroll
  for (int k = 0; k < 4; ++k) {
    int i = t * 4 + k;
    v[k] = (i < nb) ? gcount[i] : 0;
    s += v[k];
  }
  part[t] = s;
  __syncthreads();
  for (int off = 1; off < 256; off <<= 1) {
    int x = part[t];
    if (t >= off) x += part[t - off];
    __syncthreads();
    part[t] = x;
    __syncthreads();
  }
  int run = (t == 0) ? 0 : part[t - 1];
#pragma unroll
  for (int k = 0; k < 4; ++k) {
    int i = t * 4 + k;
    if (i < nb) { boff[i] = run; gcursor[i] = run; }
    run += v[k];
  }
  if (t == 255) { boff[nb] = part[255]; row_off[n] = part[255]; }
}

// ---------------- block-multisplit scatter, int4/float4 loads ----------------
#define EPB 8192
__global__ __launch_bounds__(256) void bucket_scatter(const int* __restrict__ src,
                                                      const int* __restrict__ dst,
                                                      const float* __restrict__ w,
                                                      int* __restrict__ gcursor,
                                                      uint2* __restrict__ ews, int e, int nb) {
  __shared__ int hist[NBMAX];
  __shared__ int gbase[NBMAX];
  __shared__ int lcur[NBMAX];
  const int t = threadIdx.x;
  for (int i = t; i < nb; i += 256) { hist[i] = 0; lcur[i] = 0; }
  __syncthreads();
  const int b4 = blockIdx.x * 2048;
  int4 dv[8];
#pragma unroll
  for (int k = 0; k < 8; ++k) {
    int gi = b4 + k * 256 + t;
    int e0 = gi * 4;
    int4 d = make_int4(-1, -1, -1, -1);
    if (e0 + 3 < e) d = ((const int4*)dst)[gi];
    else if (e0 < e) {
      d.x = dst[e0];
      if (e0 + 1 < e) d.y = dst[e0 + 1];
      if (e0 + 2 < e) d.z = dst[e0 + 2];
    }
    dv[k] = d;
    if (d.x >= 0) atomicAdd(&hist[d.x >> 6], 1);
    if (d.y >= 0) atomicAdd(&hist[d.y >> 6], 1);
    if (d.z >= 0) atomicAdd(&hist[d.z >> 6], 1);
    if (d.w >= 0) atomicAdd(&hist[d.w >> 6], 1);
  }
  __syncthreads();
  for (int i = t; i < nb; i += 256) {
    int c = hist[i];
    gbase[i] = c ? atomicAdd(&gcursor[i], c) : 0;
  }
  __syncthreads();
#pragma unroll
  for (int k = 0; k < 8; ++k) {
    int gi = b4 + k * 256 + t;
    int e0 = gi * 4;
    if (e0 >= e) continue;
    int4 s4 = make_int4(0, 0, 0, 0);
    float4 w4 = make_float4(0.f, 0.f, 0.f, 0.f);
    if (e0 + 3 < e) { s4 = ((const int4*)src)[gi]; w4 = ((const float4*)w)[gi]; }
    else {
      s4.x = src[e0]; w4.x = w[e0];
      if (e0 + 1 < e) { s4.y = src[e0 + 1]; w4.y = w[e0 + 1]; }
      if (e0 + 2 < e) { s4.z = src[e0 + 2]; w4.z = w[e0 + 2]; }
    }
    int4 d = dv[k];
    if (d.x >= 0) { int bb = d.x >> 6; int r = atomicAdd(&lcur[bb], 1);
      ews[gbase[bb] + r] = make_uint2(((unsigned)(d.x & 63) << 26) | (unsigned)s4.x, __float_as_uint(w4.x)); }
    if (d.y >= 0) { int bb = d.y >> 6; int r = atomicAdd(&lcur[bb], 1);
      ews[gbase[bb] + r] = make_uint2(((unsigned)(d.y & 63) << 26) | (unsigned)s4.y, __float_as_uint(w4.y)); }
    if (d.z >= 0) { int bb = d.z >> 6; int r = atomicAdd(&lcur[bb], 1);
      ews[gbase[bb] + r] = make_uint2(((unsigned)(d.z & 63) << 26) | (unsigned)s4.z, __float_as_uint(w4.z)); }
    if (d.w >= 0) { int bb = d.w >> 6; int r = atomicAdd(&lcur[bb], 1);
      ews[gbase[bb] + r] = make_uint2(((unsigned)(d.w & 63) << 26) | (unsigned)s4.w, __float_as_uint(w4.w)); }
  }
}

// ---------------- per-bucket dst-sort -> packed 4B records (src:16 | w_fp16:16) ----------------
__global__ __launch_bounds__(256) void bucket_sort(const uint2* __restrict__ ews,
                                                   const int* __restrict__ boff,
                                                   unsigned* __restrict__ ews2,
                                                   int* __restrict__ row_off,
                                                   int n) {
  __shared__ int cnt64[64];
  __shared__ int cur[64];
  const int t = threadIdx.x;
  const int b = blockIdx.x;
  const int e0 = boff[b], e1 = boff[b + 1];
  if (t < 64) cnt64[t] = 0;
  __syncthreads();
  for (int i = e0 + t; i < e1; i += 256) atomicAdd(&cnt64[(unsigned)ews[i].x >> 26], 1);
  __syncthreads();
  if (t == 0) {
    int run = 0;
    for (int d = 0; d < 64; ++d) {
      int c = cnt64[d];
      cur[d] = run;
      run += c;
    }
  }
  __syncthreads();
  if (t < 64) {
    int node = b * 64 + t;
    if (node < n) row_off[node] = e0 + cur[t];
  }
  __syncthreads();
  for (int i = e0 + t; i < e1; i += 256) {
    uint2 p = ews[i];
    int d = (unsigned)p.x >> 26;
    int pos = e0 + atomicAdd(&cur[d], 1);
    unsigned rec = (p.x & 0xFFFFu) | ((unsigned)ftof16(__uint_as_float(p.y)) << 16);
    ews2[pos] = rec;
  }
}

// decode + gather + fma for a pair of packed edge records (half selects)
#define SPMM_PAIR(ua, ub)                                                    \
  {                                                                          \
    unsigned u = half ? (ub) : (ua);                                         \
    float wt = f16tof((unsigned short)(u >> 16));                            \
    const uint2 xv = *(const uint2*)(xin + (size_t)(u & 0xFFFFu) * HDIM + fo); \
    acc.x = fmaf(wt, __uint_as_float(xv.x << 16), acc.x);                    \
    acc.y = fmaf(wt, __uint_as_float(xv.x & 0xFFFF0000u), acc.y);            \
    acc.z = fmaf(wt, __uint_as_float(xv.y << 16), acc.z);                    \
    acc.w = fmaf(wt, __uint_as_float(xv.y & 0xFFFF0000u), acc.w);            \
  }

// ---------------- SPMM1: bf16 gather, wave/node, bf16 out, relu ----------------
__global__ __launch_bounds__(256) void spmm_bf16(const unsigned short* __restrict__ xin,
                                                 const unsigned* __restrict__ ews,
                                                 const int* __restrict__ row_off,
                                                 const float* __restrict__ bias,
                                                 unsigned short* __restrict__ outp, int n) {
  const int t = threadIdx.x;
  const int l = t & 63;
  const int node = blockIdx.x * 4 + (t >> 6);
  if (node >= n) return;
  const int ue0 = __builtin_amdgcn_readfirstlane(row_off[node]);
  const int ue1 = __builtin_amdgcn_readfirstlane(row_off[node + 1]);
  const int cnt = ue1 - ue0;
  const unsigned* ep = ews + ue0;              // wave-uniform -> scalar loads
  const int fo = (l & 31) * 4;
  const int half = l >> 5;
  float4 acc = make_float4(0.f, 0.f, 0.f, 0.f);

  int k = 0;
  for (; k + 8 <= cnt; k += 8) {
    unsigned a0 = ep[k + 0], a1 = ep[k + 1], a2 = ep[k + 2], a3 = ep[k + 3];
    unsigned a4 = ep[k + 4], a5 = ep[k + 5], a6 = ep[k + 6], a7 = ep[k + 7];
    SPMM_PAIR(a0, a1);
    SPMM_PAIR(a2, a3);
    SPMM_PAIR(a4, a5);
    SPMM_PAIR(a6, a7);
  }
  for (; k < cnt; k += 2) {
    unsigned a0 = ep[k];
    unsigned a1 = (k + 1 < cnt) ? ep[k + 1] : 0u;  // w=+0, src=0 -> safe
    SPMM_PAIR(a0, a1);
  }

  acc.x += __shfl_xor(acc.x, 32, 64);
  acc.y += __shfl_xor(acc.y, 32, 64);
  acc.z += __shfl_xor(acc.z, 32, 64);
  acc.w += __shfl_xor(acc.w, 32, 64);
  if (l < 32) {
    float4 bv = *(const float4*)(bias + fo);
    float4 r = make_float4(fmaxf(acc.x + bv.x, 0.f), fmaxf(acc.y + bv.y, 0.f),
                           fmaxf(acc.z + bv.z, 0.f), fmaxf(acc.w + bv.w, 0.f));
    uint2 o = make_uint2(pkbf(r.x, r.y), pkbf(r.z, r.w));
    *(uint2*)(outp + (size_t)node * HDIM + fo) = o;
  }
}

// ---------------- SPMM2 + head fused: gather h2, shfl-broadcast, logits, softmax ----------------
// sW: rows 0..39 = Wc, rows 40..167 = Wf[128:256], then bc[40].
__global__ __launch_bounds__(256) void spmm_head(const unsigned short* __restrict__ xin,
                                                 const unsigned* __restrict__ ews,
                                                 const int* __restrict__ row_off,
                                                 const float* __restrict__ b2,
                                                 const float* __restrict__ y,
                                                 const float* __restrict__ Wc,
                                                 const float* __restrict__ bcv,
                                                 const float* __restrict__ Wf,
                                                 float* __restrict__ out, int n) {
  __shared__ float sW[169 * CCLS];
  const int t = threadIdx.x;
  for (int i = t; i < CCLS * CCLS; i += 256) sW[i] = Wc[i];
  for (int i = t; i < HDIM * CCLS; i += 256) sW[CCLS * CCLS + i] = Wf[HDIM * CCLS + i];
  if (t < CCLS) sW[168 * CCLS + t] = bcv[t];
  __syncthreads();

  const int l = t & 63;
  const int node = blockIdx.x * 4 + (t >> 6);
  if (node >= n) return;
  const int ue0 = __builtin_amdgcn_readfirstlane(row_off[node]);
  const int ue1 = __builtin_amdgcn_readfirstlane(row_off[node + 1]);
  const int cnt = ue1 - ue0;
  const unsigned* ep = ews + ue0;
  const int fo = (l & 31) * 4;
  const int half = l >> 5;
  float4 acc = make_float4(0.f, 0.f, 0.f, 0.f);

  int k = 0;
  for (; k + 8 <= cnt; k += 8) {
    unsigned a0 = ep[k + 0], a1 = ep[k + 1], a2 = ep[k + 2], a3 = ep[k + 3];
    unsigned a4 = ep[k + 4], a5 = ep[k + 5], a6 = ep[k + 6], a7 = ep[k + 7];
    SPMM_PAIR(a0, a1);
    SPMM_PAIR(a2, a3);
    SPMM_PAIR(a4, a5);
    SPMM_PAIR(a6, a7);
  }
  for (; k < cnt; k += 2) {
    unsigned a0 = ep[k];
    unsigned a1 = (k + 1 < cnt) ? ep[k + 1] : 0u;
    SPMM_PAIR(a0, a1);
  }

  // merge halves: after this ALL 64 lanes hold the full h2 fragment for fo..fo+3
  acc.x += __shfl_xor(acc.x, 32, 64);
  acc.y += __shfl_xor(acc.y, 32, 64);
  acc.z += __shfl_xor(acc.z, 32, 64);
  acc.w += __shfl_xor(acc.w, 32, 64);
  {
    float4 bv = *(const float4*)(b2 + fo);
    acc.x += bv.x; acc.y += bv.y; acc.z += bv.z; acc.w += bv.w;
  }

  // head: lane c (<40) computes logit c
  float lg = (l < CCLS) ? sW[168 * CCLS + l] : -INFINITY;
  const float* yp = y + (size_t)node * CCLS;   // wave-uniform -> scalar loads
#pragma unroll 8
  for (int j = 0; j < CCLS; ++j) {
    float yj = yp[j];
    if (l < CCLS) lg = fmaf(yj, sW[j * CCLS + l], lg);
  }
#pragma unroll
  for (int f4 = 0; f4 < 32; ++f4) {            // h2 part via shfl broadcast
    float zx = __shfl(acc.x, f4, 64);
    float zy = __shfl(acc.y, f4, 64);
    float zz = __shfl(acc.z, f4, 64);
    float zw = __shfl(acc.w, f4, 64);
    if (l < CCLS) {
      const float* wr = sW + CCLS * CCLS + (f4 * 4) * CCLS + l;
      lg = fmaf(zx, wr[0 * CCLS], lg);
      lg = fmaf(zy, wr[1 * CCLS], lg);
      lg = fmaf(zz, wr[2 * CCLS], lg);
      lg = fmaf(zw, wr[3 * CCLS], lg);
    }
  }

  // softmax across 40 logits (lanes >=40 hold -inf / 0)
  float m = lg;
#pragma unroll
  for (int off = 32; off; off >>= 1) m = fmaxf(m, __shfl_xor(m, off, 64));
  float ev = (l < CCLS) ? __expf(lg - m) : 0.f;
  float sum = ev;
#pragma unroll
  for (int off = 32; off; off >>= 1) sum += __shfl_xor(sum, off, 64);
  if (l < CCLS) out[(size_t)node * CCLS + l] = ev / sum;
}

// ---------------- MFMA GEMM: C[M][128] = A[M][K](bf16) @ WT[128][K](bf16) ----------------
template <int K>
__global__ __launch_bounds__(256) void gemm_mfma(const unsigned short* __restrict__ A,
                                                 const unsigned short* __restrict__ WT,
                                                 unsigned short* __restrict__ C, int M) {
  const int t = threadIdx.x;
  const int w = t >> 6, l = t & 63;
  const int ln = l & 15, quad = l >> 4;
  const int m0 = blockIdx.x * 64 + w * 16;
  const int arow = m0 + ln;
  const unsigned short* aptr = A + (size_t)(arow < M ? arow : (M - 1)) * K + quad * 8;

  f32x4 acc[8];
#pragma unroll
  for (int i = 0; i < 8; ++i) acc[i] = (f32x4){0.f, 0.f, 0.f, 0.f};

#pragma unroll
  for (int k0 = 0; k0 < K; k0 += 32) {
    bf16x8 af = *(const bf16x8*)(aptr + k0);
#pragma unroll
    for (int ti = 0; ti < 8; ++ti) {
      bf16x8 bf = *(const bf16x8*)(WT + (size_t)(ti * 16 + ln) * K + k0 + quad * 8);
      acc[ti] = __builtin_amdgcn_mfma_f32_16x16x32_bf16(af, bf, acc[ti], 0, 0, 0);
    }
  }

#pragma unroll
  for (int r = 0; r < 4; ++r) {
    int grow = m0 + quad * 4 + r;
    if (grow < M) {
      unsigned short* cp = C + (size_t)grow * HDIM + ln;
#pragma unroll
      for (int ti = 0; ti < 8; ++ti) cp[ti * 16] = bfr(acc[ti][r]);
    }
  }
}

extern "C" void kernel_launch(void* const* d_in, const int* in_sizes, int n_in,
                              void* d_out, int out_size, void* d_ws, size_t ws_size,
                              hipStream_t stream) {
  (void)n_in; (void)out_size; (void)ws_size;
  const float* features = (const float*)d_in[0];
  const int*   src      = (const int*)d_in[1];
  const int*   dst      = (const int*)d_in[2];
  const float* ew       = (const float*)d_in[3];
  const float* y        = (const float*)d_in[4];
  const float* W1       = (const float*)d_in[5];
  const float* b1       = (const float*)d_in[6];
  const float* W2       = (const float*)d_in[7];
  const float* b2       = (const float*)d_in[8];
  const float* We       = (const float*)d_in[9];
  const float* be       = (const float*)d_in[10];
  const float* Wf       = (const float*)d_in[11];
  const float* bf       = (const float*)d_in[12];
  float* out = (float*)d_out;

  const int n = in_sizes[0] / F_IN;   // 50000
  const int e = in_sizes[1];          // 1600000
  const int nb = (n + 63) >> 6;       // 782 buckets

  char* w = (char*)d_ws;
  auto take = [&](size_t bytes) {
    char* p = w;
    w += (bytes + 255) & ~(size_t)255;
    return p;
  };
  int*   gcount   = (int*)take((size_t)nb * 4);
  int*   boff     = (int*)take((size_t)(nb + 1) * 4);
  int*   gcursor  = (int*)take((size_t)nb * 4);
  int*   row_off  = (int*)take((size_t)(n + 1) * 4);
  uint2* ews      = (uint2*)take((size_t)e * 8);
  unsigned* ews2  = (unsigned*)take((size_t)(e + 16) * 4);
  unsigned short* featbf = (unsigned short*)take((size_t)n * F_IN * 2);
  unsigned short* bufH1  = (unsigned short*)take((size_t)n * HDIM * 2);
  unsigned short* bufH2  = (unsigned short*)take((size_t)n * HDIM * 2);
  unsigned short* W1T = (unsigned short*)take((size_t)HDIM * F_IN * 2);
  unsigned short* W2T = (unsigned short*)take((size_t)HDIM * HDIM * 2);
  float* Wc       = (float*)take(CCLS * CCLS * 4);
  float* bc       = (float*)take(CCLS * 4);

  const int nblk = (n + 3) >> 2;
  const int zb = (nb + 255) >> 8;
  prep_kernel<<<nblk + 193 + zb, 256, 0, stream>>>(features, featbf, W1, W2, W1T, W2T,
                                                   We, be, Wf, bf, Wc, bc, gcount, n, nb);
  bucket_hist<<<(e + 4095) / 4096, 256, 0, stream>>>(dst, gcount, e, nb);
  bucket_scan<<<1, 256, 0, stream>>>(gcount, boff, gcursor, row_off, nb, n);
  bucket_scatter<<<(e + EPB - 1) / EPB, 256, 0, stream>>>(src, dst, ew, gcursor, ews, e, nb);
  bucket_sort<<<nb, 256, 0, stream>>>(ews, boff, ews2, row_off, n);

  gemm_mfma<F_IN><<<(n + 63) / 64, 256, 0, stream>>>(featbf, W1T, bufH1, n);
  spmm_bf16<<<(n + 3) / 4, 256, 0, stream>>>(bufH1, ews2, row_off, b1, bufH2, n);
  gemm_mfma<HDIM><<<(n + 63) / 64, 256, 0, stream>>>(bufH2, W2T, bufH1, n);
  spmm_head<<<(n + 3) / 4, 256, 0, stream>>>(bufH1, ews2, row_off, b2, y, Wc, bc, Wf, out, n);
}

// Round 10
// 401.696 us; speedup vs baseline: 1.2997x; 1.2997x over previous
//
#include <hip/hip_runtime.h>
#include <hip/hip_bf16.h>
#include <hip/hip_fp16.h>
#include <cstdint>
#include <cstddef>
#include <cmath>

#define F_IN 256
#define HDIM 128
#define CCLS 40
#define NBMAX 1024   // max buckets (n<=65536); n=50000 -> 782

typedef short bf16x8 __attribute__((ext_vector_type(8)));
typedef float f32x4 __attribute__((ext_vector_type(4)));

__device__ inline unsigned pkbf(float a, float b) {
  __hip_bfloat162 h = __float22bfloat162_rn(make_float2(a, b));
  unsigned u;
  __builtin_memcpy(&u, &h, 4);
  return u;
}
__device__ inline unsigned short bfr(float f) {
  __hip_bfloat16 h = __float2bfloat16(f);
  unsigned short u;
  __builtin_memcpy(&u, &h, 2);
  return u;
}
__device__ inline float f16tof(unsigned short hb) {
  __half hv;
  __builtin_memcpy(&hv, &hb, 2);
  return __half2float(hv);
}
__device__ inline unsigned short ftof16(float f) {
  __half hv = __float2half(f);
  unsigned short u;
  __builtin_memcpy(&u, &hv, 2);
  return u;
}

// ---- prep: norm+bf16cast | W1T/W2T transpose | Wc fold | bucket hist (gcount pre-zeroed) ----
__global__ __launch_bounds__(256) void prep_kernel(const float* __restrict__ x,
                                                   unsigned short* __restrict__ featbf,
                                                   const float* __restrict__ W1,
                                                   const float* __restrict__ W2,
                                                   unsigned short* __restrict__ W1T,
                                                   unsigned short* __restrict__ W2T,
                                                   const float* __restrict__ We,
                                                   const float* __restrict__ be,
                                                   const float* __restrict__ Wf,
                                                   const float* __restrict__ bf,
                                                   float* __restrict__ Wc,
                                                   float* __restrict__ bc,
                                                   const int* __restrict__ dst,
                                                   int* __restrict__ gcount,
                                                   int n, int e, int nb) {
  const int b = blockIdx.x;
  const int t = threadIdx.x;
  const int nblk = (n + 3) >> 2;
  if (b < nblk) {                       // ---- row L2 norm + bf16 cast
    int wv = t >> 6, l = t & 63;
    int row = b * 4 + wv;
    if (row >= n) return;
    float4 v = *(const float4*)(x + (size_t)row * F_IN + l * 4);
    float s = v.x * v.x + v.y * v.y + v.z * v.z + v.w * v.w;
#pragma unroll
    for (int off = 32; off; off >>= 1) s += __shfl_xor(s, off, 64);
    float inv = 1.0f / fmaxf(sqrtf(s), 1e-12f);
    uint2 o = make_uint2(pkbf(v.x * inv, v.y * inv), pkbf(v.z * inv, v.w * inv));
    *(uint2*)(featbf + (size_t)row * F_IN + l * 4) = o;
  } else if (b < nblk + 192) {          // ---- W transpose + bf16
    int idx = (b - nblk) * 256 + t;
    if (idx < 128 * 256) {
      int nr = idx >> 8, k = idx & 255;
      W1T[idx] = bfr(W1[k * 128 + nr]);
    } else {
      int i2 = idx - 128 * 256;
      if (i2 < 128 * 128) {
        int nr = i2 >> 7, k = i2 & 127;
        W2T[i2] = bfr(W2[k * 128 + nr]);
      }
    }
  } else if (b == nblk + 192) {         // ---- fold Wc = We @ Wf_top, bc
    for (int i = t; i < CCLS * CCLS; i += 256) {
      int c = i / CCLS, j = i % CCLS;
      float s = 0.f;
      for (int f = 0; f < HDIM; ++f) s += We[c * HDIM + f] * Wf[f * CCLS + j];
      Wc[i] = s;
    }
    if (t < CCLS) {
      float s = bf[t];
      for (int f = 0; f < HDIM; ++f) s += be[f] * Wf[f * CCLS + t];
      bc[t] = s;
    }
  } else {                              // ---- bucket histogram
    __shared__ int h[NBMAX];
    for (int i = t; i < nb; i += 256) h[i] = 0;
    __syncthreads();
    int b4 = (b - (nblk + 193)) * 1024;
#pragma unroll
    for (int k = 0; k < 4; ++k) {
      int gi = b4 + k * 256 + t;
      int e0 = gi * 4;
      int4 d = make_int4(-1, -1, -1, -1);
      if (e0 + 3 < e) d = ((const int4*)dst)[gi];
      else if (e0 < e) {
        d.x = dst[e0];
        if (e0 + 1 < e) d.y = dst[e0 + 1];
        if (e0 + 2 < e) d.z = dst[e0 + 2];
      }
      if (d.x >= 0) atomicAdd(&h[d.x >> 6], 1);
      if (d.y >= 0) atomicAdd(&h[d.y >> 6], 1);
      if (d.z >= 0) atomicAdd(&h[d.z >> 6], 1);
      if (d.w >= 0) atomicAdd(&h[d.w >> 6], 1);
    }
    __syncthreads();
    for (int i = t; i < nb; i += 256)
      if (h[i]) atomicAdd(&gcount[i], h[i]);
  }
}

// ---------------- exclusive scan of bucket counts (1 block) ----------------
__global__ __launch_bounds__(256) void bucket_scan(const int* __restrict__ gcount,
                                                   int* __restrict__ boff,
                                                   int* __restrict__ gcursor,
                                                   int* __restrict__ row_off,
                                                   int nb, int n) {
  __shared__ int part[256];
  int t = threadIdx.x;
  int v[4];
  int s = 0;
#pragma unroll
  for (int k = 0; k < 4; ++k) {
    int i = t * 4 + k;
    v[k] = (i < nb) ? gcount[i] : 0;
    s += v[k];
  }
  part[t] = s;
  __syncthreads();
  for (int off = 1; off < 256; off <<= 1) {
    int x = part[t];
    if (t >= off) x += part[t - off];
    __syncthreads();
    part[t] = x;
    __syncthreads();
  }
  int run = (t == 0) ? 0 : part[t - 1];
#pragma unroll
  for (int k = 0; k < 4; ++k) {
    int i = t * 4 + k;
    if (i < nb) { boff[i] = run; gcursor[i] = run; }
    run += v[k];
  }
  if (t == 255) { boff[nb] = part[255]; row_off[n] = part[255]; }
}

// ---------------- block-multisplit scatter, int4/float4 loads ----------------
#define EPB 8192
__global__ __launch_bounds__(256) void bucket_scatter(const int* __restrict__ src,
                                                      const int* __restrict__ dst,
                                                      const float* __restrict__ w,
                                                      int* __restrict__ gcursor,
                                                      uint2* __restrict__ ews, int e, int nb) {
  __shared__ int hist[NBMAX];
  __shared__ int gbase[NBMAX];
  __shared__ int lcur[NBMAX];
  const int t = threadIdx.x;
  for (int i = t; i < nb; i += 256) { hist[i] = 0; lcur[i] = 0; }
  __syncthreads();
  const int b4 = blockIdx.x * 2048;
  int4 dv[8];
#pragma unroll
  for (int k = 0; k < 8; ++k) {
    int gi = b4 + k * 256 + t;
    int e0 = gi * 4;
    int4 d = make_int4(-1, -1, -1, -1);
    if (e0 + 3 < e) d = ((const int4*)dst)[gi];
    else if (e0 < e) {
      d.x = dst[e0];
      if (e0 + 1 < e) d.y = dst[e0 + 1];
      if (e0 + 2 < e) d.z = dst[e0 + 2];
    }
    dv[k] = d;
    if (d.x >= 0) atomicAdd(&hist[d.x >> 6], 1);
    if (d.y >= 0) atomicAdd(&hist[d.y >> 6], 1);
    if (d.z >= 0) atomicAdd(&hist[d.z >> 6], 1);
    if (d.w >= 0) atomicAdd(&hist[d.w >> 6], 1);
  }
  __syncthreads();
  for (int i = t; i < nb; i += 256) {
    int c = hist[i];
    gbase[i] = c ? atomicAdd(&gcursor[i], c) : 0;
  }
  __syncthreads();
#pragma unroll
  for (int k = 0; k < 8; ++k) {
    int gi = b4 + k * 256 + t;
    int e0 = gi * 4;
    if (e0 >= e) continue;
    int4 s4 = make_int4(0, 0, 0, 0);
    float4 w4 = make_float4(0.f, 0.f, 0.f, 0.f);
    if (e0 + 3 < e) { s4 = ((const int4*)src)[gi]; w4 = ((const float4*)w)[gi]; }
    else {
      s4.x = src[e0]; w4.x = w[e0];
      if (e0 + 1 < e) { s4.y = src[e0 + 1]; w4.y = w[e0 + 1]; }
      if (e0 + 2 < e) { s4.z = src[e0 + 2]; w4.z = w[e0 + 2]; }
    }
    int4 d = dv[k];
    if (d.x >= 0) { int bb = d.x >> 6; int r = atomicAdd(&lcur[bb], 1);
      ews[gbase[bb] + r] = make_uint2(((unsigned)(d.x & 63) << 26) | (unsigned)s4.x, __float_as_uint(w4.x)); }
    if (d.y >= 0) { int bb = d.y >> 6; int r = atomicAdd(&lcur[bb], 1);
      ews[gbase[bb] + r] = make_uint2(((unsigned)(d.y & 63) << 26) | (unsigned)s4.y, __float_as_uint(w4.y)); }
    if (d.z >= 0) { int bb = d.z >> 6; int r = atomicAdd(&lcur[bb], 1);
      ews[gbase[bb] + r] = make_uint2(((unsigned)(d.z & 63) << 26) | (unsigned)s4.z, __float_as_uint(w4.z)); }
    if (d.w >= 0) { int bb = d.w >> 6; int r = atomicAdd(&lcur[bb], 1);
      ews[gbase[bb] + r] = make_uint2(((unsigned)(d.w & 63) << 26) | (unsigned)s4.w, __float_as_uint(w4.w)); }
  }
}

// ---------------- per-bucket dst-sort -> packed 4B records (src:16 | w_fp16:16) ----------------
__global__ __launch_bounds__(256) void bucket_sort(const uint2* __restrict__ ews,
                                                   const int* __restrict__ boff,
                                                   unsigned* __restrict__ ews2,
                                                   int* __restrict__ row_off,
                                                   int n) {
  __shared__ int cnt64[64];
  __shared__ int cur[64];
  const int t = threadIdx.x;
  const int b = blockIdx.x;
  const int e0 = boff[b], e1 = boff[b + 1];
  if (t < 64) cnt64[t] = 0;
  __syncthreads();
  for (int i = e0 + t; i < e1; i += 256) atomicAdd(&cnt64[(unsigned)ews[i].x >> 26], 1);
  __syncthreads();
  if (t == 0) {
    int run = 0;
    for (int d = 0; d < 64; ++d) {
      int c = cnt64[d];
      cur[d] = run;
      run += c;
    }
  }
  __syncthreads();
  if (t < 64) {
    int node = b * 64 + t;
    if (node < n) row_off[node] = e0 + cur[t];
  }
  __syncthreads();
  for (int i = e0 + t; i < e1; i += 256) {
    uint2 p = ews[i];
    int d = (unsigned)p.x >> 26;
    int pos = e0 + atomicAdd(&cur[d], 1);
    unsigned rec = (p.x & 0xFFFFu) | ((unsigned)ftof16(__uint_as_float(p.y)) << 16);
    ews2[pos] = rec;
  }
}

// decode + gather + fma for a pair of packed edge records (half selects)
#define SPMM_PAIR(ua, ub)                                                      \
  {                                                                            \
    unsigned u = half ? (ub) : (ua);                                           \
    float wt = f16tof((unsigned short)(u >> 16));                              \
    const uint2 xv = *(const uint2*)(xin + (size_t)(u & 0xFFFFu) * HDIM + fo); \
    acc.x = fmaf(wt, __uint_as_float(xv.x << 16), acc.x);                      \
    acc.y = fmaf(wt, __uint_as_float(xv.x & 0xFFFF0000u), acc.y);              \
    acc.z = fmaf(wt, __uint_as_float(xv.y << 16), acc.z);                      \
    acc.w = fmaf(wt, __uint_as_float(xv.y & 0xFFFF0000u), acc.w);              \
  }

// ---------------- SPMM: bf16 gather, wave/node, packed 4B records, templated out ----------------
template <int OUT_BF16>
__global__ __launch_bounds__(256) void spmm_bf16(const unsigned short* __restrict__ xin,
                                                 const unsigned* __restrict__ ews,
                                                 const int* __restrict__ row_off,
                                                 const float* __restrict__ bias,
                                                 void* __restrict__ outp, int n,
                                                 int do_relu) {
  const int t = threadIdx.x;
  const int l = t & 63;
  const int node = blockIdx.x * 4 + (t >> 6);
  if (node >= n) return;
  const int ue0 = __builtin_amdgcn_readfirstlane(row_off[node]);
  const int ue1 = __builtin_amdgcn_readfirstlane(row_off[node + 1]);
  const int cnt = ue1 - ue0;
  const unsigned* ep = ews + ue0;              // wave-uniform -> scalar loads
  const int fo = (l & 31) * 4;
  const int half = l >> 5;
  float4 acc = make_float4(0.f, 0.f, 0.f, 0.f);

  int k = 0;
  for (; k + 8 <= cnt; k += 8) {
    unsigned a0 = ep[k + 0], a1 = ep[k + 1], a2 = ep[k + 2], a3 = ep[k + 3];
    unsigned a4 = ep[k + 4], a5 = ep[k + 5], a6 = ep[k + 6], a7 = ep[k + 7];
    SPMM_PAIR(a0, a1);
    SPMM_PAIR(a2, a3);
    SPMM_PAIR(a4, a5);
    SPMM_PAIR(a6, a7);
  }
  for (; k < cnt; k += 2) {
    unsigned a0 = ep[k];
    unsigned a1 = (k + 1 < cnt) ? ep[k + 1] : 0u;  // w=+0, src=0 -> safe
    SPMM_PAIR(a0, a1);
  }

  acc.x += __shfl_xor(acc.x, 32, 64);
  acc.y += __shfl_xor(acc.y, 32, 64);
  acc.z += __shfl_xor(acc.z, 32, 64);
  acc.w += __shfl_xor(acc.w, 32, 64);
  if (l < 32) {
    float4 bv = *(const float4*)(bias + fo);
    float4 r = make_float4(acc.x + bv.x, acc.y + bv.y, acc.z + bv.z, acc.w + bv.w);
    if (do_relu) {
      r.x = fmaxf(r.x, 0.f); r.y = fmaxf(r.y, 0.f);
      r.z = fmaxf(r.z, 0.f); r.w = fmaxf(r.w, 0.f);
    }
    if (OUT_BF16) {
      uint2 o = make_uint2(pkbf(r.x, r.y), pkbf(r.z, r.w));
      *(uint2*)((unsigned short*)outp + (size_t)node * HDIM + fo) = o;
    } else {
      *(float4*)((float*)outp + (size_t)node * HDIM + fo) = r;
    }
  }
}

// ---------------- MFMA GEMM: C[M][128] = A[M][K](bf16) @ WT[128][K](bf16) ----------------
template <int K>
__global__ __launch_bounds__(256) void gemm_mfma(const unsigned short* __restrict__ A,
                                                 const unsigned short* __restrict__ WT,
                                                 unsigned short* __restrict__ C, int M) {
  const int t = threadIdx.x;
  const int w = t >> 6, l = t & 63;
  const int ln = l & 15, quad = l >> 4;
  const int m0 = blockIdx.x * 64 + w * 16;
  const int arow = m0 + ln;
  const unsigned short* aptr = A + (size_t)(arow < M ? arow : (M - 1)) * K + quad * 8;

  f32x4 acc[8];
#pragma unroll
  for (int i = 0; i < 8; ++i) acc[i] = (f32x4){0.f, 0.f, 0.f, 0.f};

#pragma unroll
  for (int k0 = 0; k0 < K; k0 += 32) {
    bf16x8 af = *(const bf16x8*)(aptr + k0);
#pragma unroll
    for (int ti = 0; ti < 8; ++ti) {
      bf16x8 bf = *(const bf16x8*)(WT + (size_t)(ti * 16 + ln) * K + k0 + quad * 8);
      acc[ti] = __builtin_amdgcn_mfma_f32_16x16x32_bf16(af, bf, acc[ti], 0, 0, 0);
    }
  }

#pragma unroll
  for (int r = 0; r < 4; ++r) {
    int grow = m0 + quad * 4 + r;
    if (grow < M) {
      unsigned short* cp = C + (size_t)grow * HDIM + ln;
#pragma unroll
      for (int ti = 0; ti < 8; ++ti) cp[ti * 16] = bfr(acc[ti][r]);
    }
  }
}

// ---------------- head v3 (r5-proven): lane-per-node, acc[40] in regs, LDS broadcasts ----------------
__global__ __launch_bounds__(64) void head_kernel(const float* __restrict__ y,
                                                  const float* __restrict__ h2,
                                                  const float* __restrict__ Wc,
                                                  const float* __restrict__ bc,
                                                  const float* __restrict__ Wf,
                                                  float* __restrict__ out, int n) {
  __shared__ float sW[169 * CCLS];
  const int t = threadIdx.x;
  for (int i = t; i < 400; i += 64) ((float4*)sW)[i] = ((const float4*)Wc)[i];
  for (int i = t; i < 1280; i += 64)
    ((float4*)(sW + CCLS * CCLS))[i] = ((const float4*)(Wf + HDIM * CCLS))[i];
  if (t < 10) ((float4*)(sW + 168 * CCLS))[t] = ((const float4*)bc)[t];
  __syncthreads();

  const int node = blockIdx.x * 64 + t;
  const int nc = node < n ? node : n - 1;
  const float* zy = y + (size_t)nc * CCLS;
  const float* zh = h2 + (size_t)nc * HDIM;

  float acc[40];
#pragma unroll
  for (int cq = 0; cq < 10; ++cq) {
    float4 b4 = *(const float4*)&sW[168 * CCLS + cq * 4];
    acc[cq * 4 + 0] = b4.x; acc[cq * 4 + 1] = b4.y;
    acc[cq * 4 + 2] = b4.z; acc[cq * 4 + 3] = b4.w;
  }

#pragma unroll 2
  for (int kc = 0; kc < 10; ++kc) {      // y part: K = 40
    float4 zv = *(const float4*)(zy + kc * 4);
    float zj[4] = {zv.x, zv.y, zv.z, zv.w};
#pragma unroll
    for (int j = 0; j < 4; ++j) {
      const float* wr = sW + (kc * 4 + j) * CCLS;
#pragma unroll
      for (int cq = 0; cq < 10; ++cq) {
        float4 w4 = *(const float4*)(wr + cq * 4);
        acc[cq * 4 + 0] = fmaf(zj[j], w4.x, acc[cq * 4 + 0]);
        acc[cq * 4 + 1] = fmaf(zj[j], w4.y, acc[cq * 4 + 1]);
        acc[cq * 4 + 2] = fmaf(zj[j], w4.z, acc[cq * 4 + 2]);
        acc[cq * 4 + 3] = fmaf(zj[j], w4.w, acc[cq * 4 + 3]);
      }
    }
  }
#pragma unroll 2
  for (int kc = 0; kc < 32; ++kc) {      // h2 part: K = 128
    float4 zv = *(const float4*)(zh + kc * 4);
    float zj[4] = {zv.x, zv.y, zv.z, zv.w};
#pragma unroll
    for (int j = 0; j < 4; ++j) {
      const float* wr = sW + (40 + kc * 4 + j) * CCLS;
#pragma unroll
      for (int cq = 0; cq < 10; ++cq) {
        float4 w4 = *(const float4*)(wr + cq * 4);
        acc[cq * 4 + 0] = fmaf(zj[j], w4.x, acc[cq * 4 + 0]);
        acc[cq * 4 + 1] = fmaf(zj[j], w4.y, acc[cq * 4 + 1]);
        acc[cq * 4 + 2] = fmaf(zj[j], w4.z, acc[cq * 4 + 2]);
        acc[cq * 4 + 3] = fmaf(zj[j], w4.w, acc[cq * 4 + 3]);
      }
    }
  }

  // in-register softmax over 40 logits
  float m = acc[0];
#pragma unroll
  for (int c = 1; c < 40; ++c) m = fmaxf(m, acc[c]);
  float sum = 0.f;
#pragma unroll
  for (int c = 0; c < 40; ++c) { acc[c] = __expf(acc[c] - m); sum += acc[c]; }
  float inv = 1.0f / sum;
  if (node < n) {
    float* op = out + (size_t)node * CCLS;
#pragma unroll
    for (int cq = 0; cq < 10; ++cq) {
      float4 o = make_float4(acc[cq * 4 + 0] * inv, acc[cq * 4 + 1] * inv,
                             acc[cq * 4 + 2] * inv, acc[cq * 4 + 3] * inv);
      *(float4*)(op + cq * 4) = o;
    }
  }
}

extern "C" void kernel_launch(void* const* d_in, const int* in_sizes, int n_in,
                              void* d_out, int out_size, void* d_ws, size_t ws_size,
                              hipStream_t stream) {
  (void)n_in; (void)out_size; (void)ws_size;
  const float* features = (const float*)d_in[0];
  const int*   src      = (const int*)d_in[1];
  const int*   dst      = (const int*)d_in[2];
  const float* ew       = (const float*)d_in[3];
  const float* y        = (const float*)d_in[4];
  const float* W1       = (const float*)d_in[5];
  const float* b1       = (const float*)d_in[6];
  const float* W2       = (const float*)d_in[7];
  const float* b2       = (const float*)d_in[8];
  const float* We       = (const float*)d_in[9];
  const float* be       = (const float*)d_in[10];
  const float* Wf       = (const float*)d_in[11];
  const float* bf       = (const float*)d_in[12];
  float* out = (float*)d_out;

  const int n = in_sizes[0] / F_IN;   // 50000
  const int e = in_sizes[1];          // 1600000
  const int nb = (n + 63) >> 6;       // 782 buckets

  char* w = (char*)d_ws;
  auto take = [&](size_t bytes) {
    char* p = w;
    w += (bytes + 255) & ~(size_t)255;
    return p;
  };
  int*   gcount   = (int*)take((size_t)nb * 4);
  int*   boff     = (int*)take((size_t)(nb + 1) * 4);
  int*   gcursor  = (int*)take((size_t)nb * 4);
  int*   row_off  = (int*)take((size_t)(n + 1) * 4);
  uint2* ews      = (uint2*)take((size_t)e * 8);
  unsigned* ews2  = (unsigned*)take((size_t)(e + 16) * 4);
  unsigned short* featbf = (unsigned short*)take((size_t)n * F_IN * 2);
  unsigned short* bufH1  = (unsigned short*)take((size_t)n * HDIM * 2);
  unsigned short* bufH2  = (unsigned short*)take((size_t)n * HDIM * 2);
  float* bufS     = (float*)take((size_t)n * HDIM * 4);
  unsigned short* W1T = (unsigned short*)take((size_t)HDIM * F_IN * 2);
  unsigned short* W2T = (unsigned short*)take((size_t)HDIM * HDIM * 2);
  float* Wc       = (float*)take(CCLS * CCLS * 4);
  float* bc       = (float*)take(CCLS * 4);

  const int nblk = (n + 3) >> 2;
  const int hb = (e + 4095) / 4096;
  hipMemsetAsync(gcount, 0, (size_t)nb * 4, stream);
  prep_kernel<<<nblk + 193 + hb, 256, 0, stream>>>(features, featbf, W1, W2, W1T, W2T,
                                                   We, be, Wf, bf, Wc, bc, dst, gcount,
                                                   n, e, nb);
  bucket_scan<<<1, 256, 0, stream>>>(gcount, boff, gcursor, row_off, nb, n);
  bucket_scatter<<<(e + EPB - 1) / EPB, 256, 0, stream>>>(src, dst, ew, gcursor, ews, e, nb);
  bucket_sort<<<nb, 256, 0, stream>>>(ews, boff, ews2, row_off, n);

  gemm_mfma<F_IN><<<(n + 63) / 64, 256, 0, stream>>>(featbf, W1T, bufH1, n);
  spmm_bf16<1><<<(n + 3) / 4, 256, 0, stream>>>(bufH1, ews2, row_off, b1, bufH2, n, 1);
  gemm_mfma<HDIM><<<(n + 63) / 64, 256, 0, stream>>>(bufH2, W2T, bufH1, n);
  spmm_bf16<0><<<(n + 3) / 4, 256, 0, stream>>>(bufH1, ews2, row_off, b2, bufS, n, 0);
  head_kernel<<<(n + 63) / 64, 64, 0, stream>>>(y, bufS, Wc, bc, Wf, out, n);
}

// Round 11
// 373.718 us; speedup vs baseline: 1.3970x; 1.0749x over previous
//
#include <hip/hip_runtime.h>
#include <hip/hip_bf16.h>
#include <hip/hip_fp16.h>
#include <cstdint>
#include <cstddef>
#include <cmath>

#define F_IN 256
#define HDIM 128
#define CCLS 40
#define NBMAX 1024   // max buckets (n<=65536); n=50000 -> 782
#define EPB_H 16384  // edges per hist block

typedef short bf16x8 __attribute__((ext_vector_type(8)));
typedef float f32x4 __attribute__((ext_vector_type(4)));

__device__ inline unsigned pkbf(float a, float b) {
  __hip_bfloat162 h = __float22bfloat162_rn(make_float2(a, b));
  unsigned u;
  __builtin_memcpy(&u, &h, 4);
  return u;
}
__device__ inline unsigned short bfr(float f) {
  __hip_bfloat16 h = __float2bfloat16(f);
  unsigned short u;
  __builtin_memcpy(&u, &h, 2);
  return u;
}
__device__ inline float f16tof(unsigned short hb) {
  __half hv;
  __builtin_memcpy(&hv, &hb, 2);
  return __half2float(hv);
}
__device__ inline unsigned short ftof16(float f) {
  __half hv = __float2half(f);
  unsigned short u;
  __builtin_memcpy(&u, &hv, 2);
  return u;
}

// ---- prep: norm(4 rows/wave) | W1T/W2T transpose | Wc fold (2 blocks) | hist (98 blocks) ----
__global__ __launch_bounds__(256) void prep_kernel(const float* __restrict__ x,
                                                   unsigned short* __restrict__ featbf,
                                                   const float* __restrict__ W1,
                                                   const float* __restrict__ W2,
                                                   unsigned short* __restrict__ W1T,
                                                   unsigned short* __restrict__ W2T,
                                                   const float* __restrict__ We,
                                                   const float* __restrict__ be,
                                                   const float* __restrict__ Wf,
                                                   const float* __restrict__ bf,
                                                   float* __restrict__ Wc,
                                                   float* __restrict__ bc,
                                                   const int* __restrict__ dst,
                                                   int* __restrict__ gcount,
                                                   int n, int e, int nb) {
  const int b = blockIdx.x;
  const int t = threadIdx.x;
  const int nblk = (n + 15) >> 4;
  if (b < nblk) {                       // ---- row L2 norm + bf16 cast, 4 rows in flight/wave
    const int wv = t >> 6, l = t & 63;
    const int r0 = b * 16 + wv * 4;
    const bool q0 = r0 < n, q1 = r0 + 1 < n, q2 = r0 + 2 < n, q3 = r0 + 3 < n;
    const float* p = x + (size_t)r0 * F_IN + l * 4;
    float4 z = make_float4(0.f, 0.f, 0.f, 0.f);
    float4 v0 = q0 ? *(const float4*)(p) : z;
    float4 v1 = q1 ? *(const float4*)(p + F_IN) : z;
    float4 v2 = q2 ? *(const float4*)(p + 2 * F_IN) : z;
    float4 v3 = q3 ? *(const float4*)(p + 3 * F_IN) : z;
    float s0 = v0.x * v0.x + v0.y * v0.y + v0.z * v0.z + v0.w * v0.w;
    float s1 = v1.x * v1.x + v1.y * v1.y + v1.z * v1.z + v1.w * v1.w;
    float s2 = v2.x * v2.x + v2.y * v2.y + v2.z * v2.z + v2.w * v2.w;
    float s3 = v3.x * v3.x + v3.y * v3.y + v3.z * v3.z + v3.w * v3.w;
#pragma unroll
    for (int off = 32; off; off >>= 1) {
      s0 += __shfl_xor(s0, off, 64);
      s1 += __shfl_xor(s1, off, 64);
      s2 += __shfl_xor(s2, off, 64);
      s3 += __shfl_xor(s3, off, 64);
    }
    float i0 = 1.0f / fmaxf(sqrtf(s0), 1e-12f);
    float i1 = 1.0f / fmaxf(sqrtf(s1), 1e-12f);
    float i2 = 1.0f / fmaxf(sqrtf(s2), 1e-12f);
    float i3 = 1.0f / fmaxf(sqrtf(s3), 1e-12f);
    unsigned short* o = featbf + (size_t)r0 * F_IN + l * 4;
    if (q0) *(uint2*)(o) = make_uint2(pkbf(v0.x * i0, v0.y * i0), pkbf(v0.z * i0, v0.w * i0));
    if (q1) *(uint2*)(o + F_IN) = make_uint2(pkbf(v1.x * i1, v1.y * i1), pkbf(v1.z * i1, v1.w * i1));
    if (q2) *(uint2*)(o + 2 * F_IN) = make_uint2(pkbf(v2.x * i2, v2.y * i2), pkbf(v2.z * i2, v2.w * i2));
    if (q3) *(uint2*)(o + 3 * F_IN) = make_uint2(pkbf(v3.x * i3, v3.y * i3), pkbf(v3.z * i3, v3.w * i3));
  } else if (b < nblk + 192) {          // ---- W transpose + bf16
    int idx = (b - nblk) * 256 + t;
    if (idx < 128 * 256) {
      int nr = idx >> 8, k = idx & 255;
      W1T[idx] = bfr(W1[k * 128 + nr]);
    } else {
      int i2 = idx - 128 * 256;
      if (i2 < 128 * 128) {
        int nr = i2 >> 7, k = i2 & 127;
        W2T[i2] = bfr(W2[k * 128 + nr]);
      }
    }
  } else if (b < nblk + 194) {          // ---- fold Wc = We @ Wf_top, bc (2 blocks)
    int part = b - (nblk + 192);
    int lo = part * 800, hi = lo + 800;
    for (int i = lo + t; i < hi; i += 256) {
      int c = i / CCLS, j = i % CCLS;
      float s = 0.f;
      for (int f = 0; f < HDIM; ++f) s += We[c * HDIM + f] * Wf[f * CCLS + j];
      Wc[i] = s;
    }
    if (part == 0 && t < CCLS) {
      float s = bf[t];
      for (int f = 0; f < HDIM; ++f) s += be[f] * Wf[f * CCLS + t];
      bc[t] = s;
    }
  } else {                              // ---- bucket histogram, 16384 edges/block
    __shared__ int h[NBMAX];
    for (int i = t; i < nb; i += 256) h[i] = 0;
    __syncthreads();
    int b4 = (b - (nblk + 194)) * (EPB_H / 4);
#pragma unroll
    for (int k = 0; k < EPB_H / 1024; ++k) {
      int gi = b4 + k * 256 + t;
      int e0 = gi * 4;
      int4 d = make_int4(-1, -1, -1, -1);
      if (e0 + 3 < e) d = ((const int4*)dst)[gi];
      else if (e0 < e) {
        d.x = dst[e0];
        if (e0 + 1 < e) d.y = dst[e0 + 1];
        if (e0 + 2 < e) d.z = dst[e0 + 2];
      }
      if (d.x >= 0) atomicAdd(&h[d.x >> 6], 1);
      if (d.y >= 0) atomicAdd(&h[d.y >> 6], 1);
      if (d.z >= 0) atomicAdd(&h[d.z >> 6], 1);
      if (d.w >= 0) atomicAdd(&h[d.w >> 6], 1);
    }
    __syncthreads();
    for (int i = t; i < nb; i += 256)
      if (h[i]) atomicAdd(&gcount[i], h[i]);
  }
}

// ---------------- exclusive scan of bucket counts (1 block) ----------------
__global__ __launch_bounds__(256) void bucket_scan(const int* __restrict__ gcount,
                                                   int* __restrict__ boff,
                                                   int* __restrict__ gcursor,
                                                   int* __restrict__ row_off,
                                                   int nb, int n) {
  __shared__ int part[256];
  int t = threadIdx.x;
  int v[4];
  int s = 0;
#pragma unroll
  for (int k = 0; k < 4; ++k) {
    int i = t * 4 + k;
    v[k] = (i < nb) ? gcount[i] : 0;
    s += v[k];
  }
  part[t] = s;
  __syncthreads();
  for (int off = 1; off < 256; off <<= 1) {
    int x = part[t];
    if (t >= off) x += part[t - off];
    __syncthreads();
    part[t] = x;
    __syncthreads();
  }
  int run = (t == 0) ? 0 : part[t - 1];
#pragma unroll
  for (int k = 0; k < 4; ++k) {
    int i = t * 4 + k;
    if (i < nb) { boff[i] = run; gcursor[i] = run; }
    run += v[k];
  }
  if (t == 255) { boff[nb] = part[255]; row_off[n] = part[255]; }
}

// ---------------- block-multisplit scatter, int4/float4 loads ----------------
#define EPB 8192
__global__ __launch_bounds__(256) void bucket_scatter(const int* __restrict__ src,
                                                      const int* __restrict__ dst,
                                                      const float* __restrict__ w,
                                                      int* __restrict__ gcursor,
                                                      uint2* __restrict__ ews, int e, int nb) {
  __shared__ int hist[NBMAX];
  __shared__ int gbase[NBMAX];
  __shared__ int lcur[NBMAX];
  const int t = threadIdx.x;
  for (int i = t; i < nb; i += 256) { hist[i] = 0; lcur[i] = 0; }
  __syncthreads();
  const int b4 = blockIdx.x * 2048;
  int4 dv[8];
#pragma unroll
  for (int k = 0; k < 8; ++k) {
    int gi = b4 + k * 256 + t;
    int e0 = gi * 4;
    int4 d = make_int4(-1, -1, -1, -1);
    if (e0 + 3 < e) d = ((const int4*)dst)[gi];
    else if (e0 < e) {
      d.x = dst[e0];
      if (e0 + 1 < e) d.y = dst[e0 + 1];
      if (e0 + 2 < e) d.z = dst[e0 + 2];
    }
    dv[k] = d;
    if (d.x >= 0) atomicAdd(&hist[d.x >> 6], 1);
    if (d.y >= 0) atomicAdd(&hist[d.y >> 6], 1);
    if (d.z >= 0) atomicAdd(&hist[d.z >> 6], 1);
    if (d.w >= 0) atomicAdd(&hist[d.w >> 6], 1);
  }
  __syncthreads();
  for (int i = t; i < nb; i += 256) {
    int c = hist[i];
    gbase[i] = c ? atomicAdd(&gcursor[i], c) : 0;
  }
  __syncthreads();
#pragma unroll
  for (int k = 0; k < 8; ++k) {
    int gi = b4 + k * 256 + t;
    int e0 = gi * 4;
    if (e0 >= e) continue;
    int4 s4 = make_int4(0, 0, 0, 0);
    float4 w4 = make_float4(0.f, 0.f, 0.f, 0.f);
    if (e0 + 3 < e) { s4 = ((const int4*)src)[gi]; w4 = ((const float4*)w)[gi]; }
    else {
      s4.x = src[e0]; w4.x = w[e0];
      if (e0 + 1 < e) { s4.y = src[e0 + 1]; w4.y = w[e0 + 1]; }
      if (e0 + 2 < e) { s4.z = src[e0 + 2]; w4.z = w[e0 + 2]; }
    }
    int4 d = dv[k];
    if (d.x >= 0) { int bb = d.x >> 6; int r = atomicAdd(&lcur[bb], 1);
      ews[gbase[bb] + r] = make_uint2(((unsigned)(d.x & 63) << 26) | (unsigned)s4.x, __float_as_uint(w4.x)); }
    if (d.y >= 0) { int bb = d.y >> 6; int r = atomicAdd(&lcur[bb], 1);
      ews[gbase[bb] + r] = make_uint2(((unsigned)(d.y & 63) << 26) | (unsigned)s4.y, __float_as_uint(w4.y)); }
    if (d.z >= 0) { int bb = d.z >> 6; int r = atomicAdd(&lcur[bb], 1);
      ews[gbase[bb] + r] = make_uint2(((unsigned)(d.z & 63) << 26) | (unsigned)s4.z, __float_as_uint(w4.z)); }
    if (d.w >= 0) { int bb = d.w >> 6; int r = atomicAdd(&lcur[bb], 1);
      ews[gbase[bb] + r] = make_uint2(((unsigned)(d.w & 63) << 26) | (unsigned)s4.w, __float_as_uint(w4.w)); }
  }
}

// ---------------- per-bucket dst-sort -> packed 4B records (src:16 | w_fp16:16) ----------------
__global__ __launch_bounds__(256) void bucket_sort(const uint2* __restrict__ ews,
                                                   const int* __restrict__ boff,
                                                   unsigned* __restrict__ ews2,
                                                   int* __restrict__ row_off,
                                                   int n) {
  __shared__ int cnt64[64];
  __shared__ int cur[64];
  const int t = threadIdx.x;
  const int b = blockIdx.x;
  const int e0 = boff[b], e1 = boff[b + 1];
  if (t < 64) cnt64[t] = 0;
  __syncthreads();
  for (int i = e0 + t; i < e1; i += 256) atomicAdd(&cnt64[(unsigned)ews[i].x >> 26], 1);
  __syncthreads();
  if (t == 0) {
    int run = 0;
    for (int d = 0; d < 64; ++d) {
      int c = cnt64[d];
      cur[d] = run;
      run += c;
    }
  }
  __syncthreads();
  if (t < 64) {
    int node = b * 64 + t;
    if (node < n) row_off[node] = e0 + cur[t];
  }
  __syncthreads();
  for (int i = e0 + t; i < e1; i += 256) {
    uint2 p = ews[i];
    int d = (unsigned)p.x >> 26;
    int pos = e0 + atomicAdd(&cur[d], 1);
    unsigned rec = (p.x & 0xFFFFu) | ((unsigned)ftof16(__uint_as_float(p.y)) << 16);
    ews2[pos] = rec;
  }
}

// decode + gather + fma for a pair of packed edge records (half selects)
#define SPMM_PAIR(ua, ub)                                                      \
  {                                                                            \
    unsigned u = half ? (ub) : (ua);                                           \
    float wt = f16tof((unsigned short)(u >> 16));                              \
    const uint2 xv = *(const uint2*)(xin + (size_t)(u & 0xFFFFu) * HDIM + fo); \
    acc.x = fmaf(wt, __uint_as_float(xv.x << 16), acc.x);                      \
    acc.y = fmaf(wt, __uint_as_float(xv.x & 0xFFFF0000u), acc.y);              \
    acc.z = fmaf(wt, __uint_as_float(xv.y << 16), acc.z);                      \
    acc.w = fmaf(wt, __uint_as_float(xv.y & 0xFFFF0000u), acc.w);              \
  }

// ---------------- SPMM: bf16 gather, wave/node, packed 4B records, templated out ----------------
template <int OUT_BF16>
__global__ __launch_bounds__(256) void spmm_bf16(const unsigned short* __restrict__ xin,
                                                 const unsigned* __restrict__ ews,
                                                 const int* __restrict__ row_off,
                                                 const float* __restrict__ bias,
                                                 void* __restrict__ outp, int n,
                                                 int do_relu) {
  const int t = threadIdx.x;
  const int l = t & 63;
  const int node = blockIdx.x * 4 + (t >> 6);
  if (node >= n) return;
  const int ue0 = __builtin_amdgcn_readfirstlane(row_off[node]);
  const int ue1 = __builtin_amdgcn_readfirstlane(row_off[node + 1]);
  const int cnt = ue1 - ue0;
  const unsigned* ep = ews + ue0;              // wave-uniform -> scalar loads
  const int fo = (l & 31) * 4;
  const int half = l >> 5;
  float4 acc = make_float4(0.f, 0.f, 0.f, 0.f);

  int k = 0;
  for (; k + 8 <= cnt; k += 8) {
    unsigned a0 = ep[k + 0], a1 = ep[k + 1], a2 = ep[k + 2], a3 = ep[k + 3];
    unsigned a4 = ep[k + 4], a5 = ep[k + 5], a6 = ep[k + 6], a7 = ep[k + 7];
    SPMM_PAIR(a0, a1);
    SPMM_PAIR(a2, a3);
    SPMM_PAIR(a4, a5);
    SPMM_PAIR(a6, a7);
  }
  for (; k < cnt; k += 2) {
    unsigned a0 = ep[k];
    unsigned a1 = (k + 1 < cnt) ? ep[k + 1] : 0u;  // w=+0, src=0 -> safe
    SPMM_PAIR(a0, a1);
  }

  acc.x += __shfl_xor(acc.x, 32, 64);
  acc.y += __shfl_xor(acc.y, 32, 64);
  acc.z += __shfl_xor(acc.z, 32, 64);
  acc.w += __shfl_xor(acc.w, 32, 64);
  if (l < 32) {
    float4 bv = *(const float4*)(bias + fo);
    float4 r = make_float4(acc.x + bv.x, acc.y + bv.y, acc.z + bv.z, acc.w + bv.w);
    if (do_relu) {
      r.x = fmaxf(r.x, 0.f); r.y = fmaxf(r.y, 0.f);
      r.z = fmaxf(r.z, 0.f); r.w = fmaxf(r.w, 0.f);
    }
    if (OUT_BF16) {
      uint2 o = make_uint2(pkbf(r.x, r.y), pkbf(r.z, r.w));
      *(uint2*)((unsigned short*)outp + (size_t)node * HDIM + fo) = o;
    } else {
      *(float4*)((float*)outp + (size_t)node * HDIM + fo) = r;
    }
  }
}

// ---------------- MFMA GEMM: C[M][128] = A[M][K](bf16) @ WT[128][K](bf16) ----------------
template <int K>
__global__ __launch_bounds__(256) void gemm_mfma(const unsigned short* __restrict__ A,
                                                 const unsigned short* __restrict__ WT,
                                                 unsigned short* __restrict__ C, int M) {
  const int t = threadIdx.x;
  const int w = t >> 6, l = t & 63;
  const int ln = l & 15, quad = l >> 4;
  const int m0 = blockIdx.x * 64 + w * 16;
  const int arow = m0 + ln;
  const unsigned short* aptr = A + (size_t)(arow < M ? arow : (M - 1)) * K + quad * 8;

  f32x4 acc[8];
#pragma unroll
  for (int i = 0; i < 8; ++i) acc[i] = (f32x4){0.f, 0.f, 0.f, 0.f};

#pragma unroll
  for (int k0 = 0; k0 < K; k0 += 32) {
    bf16x8 af = *(const bf16x8*)(aptr + k0);
#pragma unroll
    for (int ti = 0; ti < 8; ++ti) {
      bf16x8 bf = *(const bf16x8*)(WT + (size_t)(ti * 16 + ln) * K + k0 + quad * 8);
      acc[ti] = __builtin_amdgcn_mfma_f32_16x16x32_bf16(af, bf, acc[ti], 0, 0, 0);
    }
  }

#pragma unroll
  for (int r = 0; r < 4; ++r) {
    int grow = m0 + quad * 4 + r;
    if (grow < M) {
      unsigned short* cp = C + (size_t)grow * HDIM + ln;
#pragma unroll
      for (int ti = 0; ti < 8; ++ti) cp[ti * 16] = bfr(acc[ti][r]);
    }
  }
}

// ---------------- head v3 (r5-proven): lane-per-node, acc[40] in regs, LDS broadcasts ----------------
__global__ __launch_bounds__(64) void head_kernel(const float* __restrict__ y,
                                                  const float* __restrict__ h2,
                                                  const float* __restrict__ Wc,
                                                  const float* __restrict__ bc,
                                                  const float* __restrict__ Wf,
                                                  float* __restrict__ out, int n) {
  __shared__ float sW[169 * CCLS];
  const int t = threadIdx.x;
  for (int i = t; i < 400; i += 64) ((float4*)sW)[i] = ((const float4*)Wc)[i];
  for (int i = t; i < 1280; i += 64)
    ((float4*)(sW + CCLS * CCLS))[i] = ((const float4*)(Wf + HDIM * CCLS))[i];
  if (t < 10) ((float4*)(sW + 168 * CCLS))[t] = ((const float4*)bc)[t];
  __syncthreads();

  const int node = blockIdx.x * 64 + t;
  const int nc = node < n ? node : n - 1;
  const float* zy = y + (size_t)nc * CCLS;
  const float* zh = h2 + (size_t)nc * HDIM;

  float acc[40];
#pragma unroll
  for (int cq = 0; cq < 10; ++cq) {
    float4 b4 = *(const float4*)&sW[168 * CCLS + cq * 4];
    acc[cq * 4 + 0] = b4.x; acc[cq * 4 + 1] = b4.y;
    acc[cq * 4 + 2] = b4.z; acc[cq * 4 + 3] = b4.w;
  }

#pragma unroll 2
  for (int kc = 0; kc < 10; ++kc) {      // y part: K = 40
    float4 zv = *(const float4*)(zy + kc * 4);
    float zj[4] = {zv.x, zv.y, zv.z, zv.w};
#pragma unroll
    for (int j = 0; j < 4; ++j) {
      const float* wr = sW + (kc * 4 + j) * CCLS;
#pragma unroll
      for (int cq = 0; cq < 10; ++cq) {
        float4 w4 = *(const float4*)(wr + cq * 4);
        acc[cq * 4 + 0] = fmaf(zj[j], w4.x, acc[cq * 4 + 0]);
        acc[cq * 4 + 1] = fmaf(zj[j], w4.y, acc[cq * 4 + 1]);
        acc[cq * 4 + 2] = fmaf(zj[j], w4.z, acc[cq * 4 + 2]);
        acc[cq * 4 + 3] = fmaf(zj[j], w4.w, acc[cq * 4 + 3]);
      }
    }
  }
#pragma unroll 2
  for (int kc = 0; kc < 32; ++kc) {      // h2 part: K = 128
    float4 zv = *(const float4*)(zh + kc * 4);
    float zj[4] = {zv.x, zv.y, zv.z, zv.w};
#pragma unroll
    for (int j = 0; j < 4; ++j) {
      const float* wr = sW + (40 + kc * 4 + j) * CCLS;
#pragma unroll
      for (int cq = 0; cq < 10; ++cq) {
        float4 w4 = *(const float4*)(wr + cq * 4);
        acc[cq * 4 + 0] = fmaf(zj[j], w4.x, acc[cq * 4 + 0]);
        acc[cq * 4 + 1] = fmaf(zj[j], w4.y, acc[cq * 4 + 1]);
        acc[cq * 4 + 2] = fmaf(zj[j], w4.z, acc[cq * 4 + 2]);
        acc[cq * 4 + 3] = fmaf(zj[j], w4.w, acc[cq * 4 + 3]);
      }
    }
  }

  // in-register softmax over 40 logits
  float m = acc[0];
#pragma unroll
  for (int c = 1; c < 40; ++c) m = fmaxf(m, acc[c]);
  float sum = 0.f;
#pragma unroll
  for (int c = 0; c < 40; ++c) { acc[c] = __expf(acc[c] - m); sum += acc[c]; }
  float inv = 1.0f / sum;
  if (node < n) {
    float* op = out + (size_t)node * CCLS;
#pragma unroll
    for (int cq = 0; cq < 10; ++cq) {
      float4 o = make_float4(acc[cq * 4 + 0] * inv, acc[cq * 4 + 1] * inv,
                             acc[cq * 4 + 2] * inv, acc[cq * 4 + 3] * inv);
      *(float4*)(op + cq * 4) = o;
    }
  }
}

extern "C" void kernel_launch(void* const* d_in, const int* in_sizes, int n_in,
                              void* d_out, int out_size, void* d_ws, size_t ws_size,
                              hipStream_t stream) {
  (void)n_in; (void)out_size; (void)ws_size;
  const float* features = (const float*)d_in[0];
  const int*   src      = (const int*)d_in[1];
  const int*   dst      = (const int*)d_in[2];
  const float* ew       = (const float*)d_in[3];
  const float* y        = (const float*)d_in[4];
  const float* W1       = (const float*)d_in[5];
  const float* b1       = (const float*)d_in[6];
  const float* W2       = (const float*)d_in[7];
  const float* b2       = (const float*)d_in[8];
  const float* We       = (const float*)d_in[9];
  const float* be       = (const float*)d_in[10];
  const float* Wf       = (const float*)d_in[11];
  const float* bf       = (const float*)d_in[12];
  float* out = (float*)d_out;

  const int n = in_sizes[0] / F_IN;   // 50000
  const int e = in_sizes[1];          // 1600000
  const int nb = (n + 63) >> 6;       // 782 buckets

  char* w = (char*)d_ws;
  auto take = [&](size_t bytes) {
    char* p = w;
    w += (bytes + 255) & ~(size_t)255;
    return p;
  };
  int*   gcount   = (int*)take((size_t)nb * 4);
  int*   boff     = (int*)take((size_t)(nb + 1) * 4);
  int*   gcursor  = (int*)take((size_t)nb * 4);
  int*   row_off  = (int*)take((size_t)(n + 1) * 4);
  uint2* ews      = (uint2*)take((size_t)e * 8);
  unsigned* ews2  = (unsigned*)take((size_t)(e + 16) * 4);
  unsigned short* featbf = (unsigned short*)take((size_t)n * F_IN * 2);
  unsigned short* bufH1  = (unsigned short*)take((size_t)n * HDIM * 2);
  unsigned short* bufH2  = (unsigned short*)take((size_t)n * HDIM * 2);
  float* bufS     = (float*)take((size_t)n * HDIM * 4);
  unsigned short* W1T = (unsigned short*)take((size_t)HDIM * F_IN * 2);
  unsigned short* W2T = (unsigned short*)take((size_t)HDIM * HDIM * 2);
  float* Wc       = (float*)take(CCLS * CCLS * 4);
  float* bc       = (float*)take(CCLS * 4);

  const int nblk = (n + 15) >> 4;
  const int hb = (e + EPB_H - 1) / EPB_H;
  hipMemsetAsync(gcount, 0, (size_t)nb * 4, stream);
  prep_kernel<<<nblk + 194 + hb, 256, 0, stream>>>(features, featbf, W1, W2, W1T, W2T,
                                                   We, be, Wf, bf, Wc, bc, dst, gcount,
                                                   n, e, nb);
  bucket_scan<<<1, 256, 0, stream>>>(gcount, boff, gcursor, row_off, nb, n);
  bucket_scatter<<<(e + EPB - 1) / EPB, 256, 0, stream>>>(src, dst, ew, gcursor, ews, e, nb);
  bucket_sort<<<nb, 256, 0, stream>>>(ews, boff, ews2, row_off, n);

  gemm_mfma<F_IN><<<(n + 63) / 64, 256, 0, stream>>>(featbf, W1T, bufH1, n);
  spmm_bf16<1><<<(n + 3) / 4, 256, 0, stream>>>(bufH1, ews2, row_off, b1, bufH2, n, 1);
  gemm_mfma<HDIM><<<(n + 63) / 64, 256, 0, stream>>>(bufH2, W2T, bufH1, n);
  spmm_bf16<0><<<(n + 3) / 4, 256, 0, stream>>>(bufH1, ews2, row_off, b2, bufS, n, 0);
  head_kernel<<<(n + 63) / 64, 64, 0, stream>>>(y, bufS, Wc, bc, Wf, out, n);
}